// Round 8
// baseline (142.520 us; speedup 1.0000x reference)
//
#include <hip/hip_runtime.h>
#include <cstdint>
#include <cstddef>

typedef float f32x4 __attribute__((ext_vector_type(4)));
typedef float f32x2 __attribute__((ext_vector_type(2)));
typedef __bf16 bf16x8 __attribute__((ext_vector_type(8)));
typedef __bf16 bf16x2 __attribute__((ext_vector_type(2)));
typedef uint32_t u32x4 __attribute__((ext_vector_type(4)));

#define TSS 9216
#define VST 9344  // O-plane row stride (bf16 elements)
#define VSF 9472  // fp8 plane stride (bytes), 16B-multiple
#define XST 72    // proj X^T LDS row stride (bf16)
#define WST 72    // out_proj W-chunk row stride (bf16)
#define RSTD 68   // out_proj A-chunk row stride in DWORDS
#define EPS 68    // proj epilogue LDS row stride (BYTES): 17 dwords, conflict-free transpose

#define FP8_SCALE 32.0f   // V,Q,K stored as fp8 of 32*value (kills denormal flush)

__device__ __forceinline__ uint32_t pack2bf(float a, float b) {
  bf16x2 v = { (__bf16)a, (__bf16)b };   // native v_cvt_pk_bf16_f32 (RNE)
  return __builtin_bit_cast(uint32_t, v);
}
__device__ __forceinline__ uint32_t pack4fp8(float a, float b, float c, float d) {
  uint32_t r = __builtin_amdgcn_cvt_pk_fp8_f32(a, b, 0, false);
  return (uint32_t)__builtin_amdgcn_cvt_pk_fp8_f32(c, d, (int)r, true);
}
// 4 packed fp8 -> 4 bf16, NO scale (x32 carried through; folded into softmax inv)
__device__ __forceinline__ uint2 fp8x4_to_bf16x4_ns(uint32_t v) {
  const f32x2 lo = __builtin_amdgcn_cvt_pk_f32_fp8((int)v, false);
  const f32x2 hi = __builtin_amdgcn_cvt_pk_f32_fp8((int)v, true);
  return uint2{pack2bf(lo[0], lo[1]), pack2bf(hi[0], hi[1])};
}

// ---------------- Kernel 0: one-time W pre-conversion ----------------
__global__ __launch_bounds__(256, 8) void wcvt_kernel(
    const float* __restrict__ w_vkq, const float* __restrict__ w_out,
    uint16_t* __restrict__ wbf, uint16_t* __restrict__ wob)
{
  const int i = blockIdx.x * 256 + threadIdx.x;
  if (i < 24576) {          // 24576 float4 = 1536*64 floats of w_vkq
    const float4 v = ((const float4*)w_vkq)[i];
    ((uint2*)wbf)[i] = uint2{pack2bf(v.x * FP8_SCALE, v.y * FP8_SCALE),
                             pack2bf(v.z * FP8_SCALE, v.w * FP8_SCALE)};
  } else {                  // 8192 float4 = 64*512 floats of w_out
    const int j = i - 24576;
    const float4 v = ((const float4*)w_out)[j];
    ((uint2*)wob)[j] = uint2{pack2bf(v.x, v.y), pack2bf(v.z, v.w)};
  }
}

// ---------------- Kernel 1: projection -> fp8 V/Q/K planes (R4-exact, measured best) --------
__global__ __launch_bounds__(256, 4) void proj_kernel(
    const float* __restrict__ x, const uint16_t* __restrict__ wbf,
    const float* __restrict__ b_vkq,
    uint8_t* __restrict__ Vr, uint8_t* __restrict__ Qr, uint8_t* __restrict__ Kr)
{
  __shared__ __align__(16) uint16_t Bt[64 * XST];      // X^T tile [p][c] bf16 (9.2 KB)
  __shared__ __align__(16) uint8_t  Ep[4][16 * EPS];   // per-wave transpose scratch (4.3 KB)

  const int t   = threadIdx.x;
  const int blk = blockIdx.x;        // 2304; XCD-grouped: oq in bits [3:4], low 3 bits = bn%8
  const int oq  = (blk >> 3) & 3;
  const int bn  = (blk & 7) | ((blk >> 5) << 3);
  const int nt  = bn % 144;
  const int b   = bn / 144;
  const int n0  = nt * 64;

  {
    const float* __restrict__ xb = x + (size_t)b * 64 * TSS + n0;
    const int p  = t & 63;
    const int c0 = (t >> 6) * 16;
    float v[16];
    #pragma unroll
    for (int i = 0; i < 16; ++i) v[i] = xb[(size_t)(c0 + i) * TSS + p];
    #pragma unroll
    for (int h = 0; h < 2; ++h)
      *(uint4*)&Bt[p * XST + c0 + h*8] =
        uint4{pack2bf(v[h*8+0], v[h*8+1]), pack2bf(v[h*8+2], v[h*8+3]),
              pack2bf(v[h*8+4], v[h*8+5]), pack2bf(v[h*8+6], v[h*8+7])};
  }
  __syncthreads();

  const int L    = t & 63;
  const int w    = t >> 6;
  const int lcol = L & 15;
  const int lq   = L >> 4;

  bf16x8 af[4][2];   // A = X^T, m = p (4 tiles of 16) — invariant all 6 o-tiles
  #pragma unroll
  for (int tm = 0; tm < 4; ++tm)
    #pragma unroll
    for (int ks = 0; ks < 2; ++ks)
      af[tm][ks] = *(const bf16x8*)&Bt[(tm*16 + lcol) * XST + ks*32 + lq*8];

  const int obase = oq * 384 + w * 96;   // wave's 6 o-tiles

  bf16x8 bw[3][2];
  float  bias_r[3];
  #pragma unroll
  for (int pre = 0; pre < 3; ++pre) {
    const int o = obase + pre*16 + lcol;
    #pragma unroll
    for (int ks = 0; ks < 2; ++ks)
      bw[pre][ks] = *(const bf16x8*)(wbf + (size_t)o * 64 + ks*32 + lq*8);
    bias_r[pre] = b_vkq[o] * FP8_SCALE;
  }

  uint8_t* __restrict__ ep = Ep[w];

  #pragma unroll
  for (int ot = 0; ot < 6; ++ot) {
    const int s3   = ot % 3;
    const float bias = bias_r[s3];
    f32x4 acc[4];
    #pragma unroll
    for (int tm = 0; tm < 4; ++tm) acc[tm] = f32x4{bias, bias, bias, bias};
    #pragma unroll
    for (int tm = 0; tm < 4; ++tm)
      #pragma unroll
      for (int ks = 0; ks < 2; ++ks)
        acc[tm] = __builtin_amdgcn_mfma_f32_16x16x32_bf16(af[tm][ks], bw[s3][ks], acc[tm], 0, 0, 0);
    if (ot < 3) {
      const int on = obase + (ot + 3)*16 + lcol;
      #pragma unroll
      for (int ks = 0; ks < 2; ++ks)
        bw[s3][ks] = *(const bf16x8*)(wbf + (size_t)on * 64 + ks*32 + lq*8);
      bias_r[s3] = b_vkq[on] * FP8_SCALE;
    }
    // transpose D[p][o] -> [o][p] through wave-private LDS (in-order per wave, no barrier)
    #pragma unroll
    for (int tm = 0; tm < 4; ++tm)
      *(uint32_t*)&ep[lcol * EPS + tm*16 + lq*4] =
        pack4fp8(acc[tm][0], acc[tm][1], acc[tm][2], acc[tm][3]);

    const int o_t  = obase + ot * 16;
    const int sreg = o_t >> 9;   // 0=V 1=Q 2=K (16-tile never straddles a 512 boundary)
    uint8_t* __restrict__ reg = (sreg == 0) ? Vr : ((sreg == 1) ? Qr : Kr);
    const size_t rb = (size_t)(b * 512 + (o_t & 511)) * VSF + n0;
    #pragma unroll
    for (int s = 0; s < 4; ++s) {
      const int orow = s*4 + lq;
      const uint32_t d = *(const uint32_t*)&ep[orow * EPS + lcol*4];
      *(uint32_t*)(reg + rb + (size_t)orow * VSF + lcol*4) = d;   // 4 full 64-B rows / instr
    }
  }
}

// ---------------- Kernel 2: attention (R7-exact). Launched TWICE this round as an
// idempotent timing probe: dur_us = base + T_attn. ------------------------------------------
__global__ __launch_bounds__(384, 4) void attn_kernel(
    const uint8_t* __restrict__ Vr, const uint8_t* __restrict__ Qr,
    const uint8_t* __restrict__ Kr, uint16_t* __restrict__ Obuf)
{
  __shared__ __align__(16) uint8_t KQ[29952];

  const int t   = threadIdx.x;
  const int blk = blockIdx.x;
  const int b   = blk >> 9;
  const int hc  = blk & 511;
  const size_t pb8 = (size_t)(b * 512 + hc) * VSF;
  const uint8_t* __restrict__ vplane = Vr + pb8;

  const uint4* __restrict__ sk = (const uint4*)(Kr + pb8);
  const uint4* __restrict__ sq = (const uint4*)(Qr + pb8);

  // stage K now; issue Q loads now but hold in regs (LDS write deferred past QK^T)
  uint4 q0, q1;
  const int r0 = t / 6, s0 = t % 6;
  int r1 = 0, s1 = 0;
  q0 = sq[t];
  *(uint4*)&KQ[9984 + r0 * 104 + s0 * 16] = sk[t];
  if (t < 192) {
    const int g = t + 384;
    r1 = g / 6; s1 = g % 6;
    q1 = sq[g];
    *(uint4*)&KQ[9984 + r1 * 104 + s1 * 16] = sk[g];
  }

  const int L    = t & 63;
  const int w    = t / 64;
  const int lcol = L & 15;
  const int lq   = L >> 4;
  const int xrow = 16 * w + lcol;
  // scores carry FP8_SCALE^2 = 1024x; fold into exp2 constant
  const float C  = 1.44269504088896f / (9216.0f * (FP8_SCALE * FP8_SCALE));
  const f32x4 zero4 = {0.f, 0.f, 0.f, 0.f};

  // V B-frags straight from global (own rows only): 8 consecutive fp8 = one b64
  long bv[3];
  #pragma unroll
  for (int ks = 0; ks < 3; ++ks)
    bv[ks] = *(const long*)(vplane + (size_t)xrow * 96 + ks*32 + lq*8);

  __syncthreads();   // barrier A: K staged (Q loads drain here too, but writes are deferred)

  // scores D[z][x]: A = K z-tiles, B = V x-rows (fp8 MFMA)
  f32x4 sa[6];
  #pragma unroll
  for (int i = 0; i < 6; ++i) sa[i] = zero4;
  #pragma unroll
  for (int tz = 0; tz < 6; ++tz)
    #pragma unroll
    for (int ks = 0; ks < 3; ++ks) {
      const long ak = *(const long*)&KQ[9984 + (tz*16 + lcol) * 104 + ks*32 + lq*8];
      sa[tz] = __builtin_amdgcn_mfma_f32_16x16x32_fp8_fp8(ak, bv[ks], sa[tz], 0, 0, 0);
    }

  // write Q (fp8) to its own LDS region — races nothing (region unused until after
  // barrier B); ds-write latency hides under the softmax VALU below
  *(uint4*)&KQ[r0 * 104 + s0 * 16] = q0;
  if (t < 192)
    *(uint4*)&KQ[r1 * 104 + s1 * 16] = q1;

  // softmax over z (|s_true| <= 0.007 -> max-subtraction safely dropped)
  float s = 0.f;
  #pragma unroll
  for (int tz = 0; tz < 6; ++tz)
    #pragma unroll
    for (int r = 0; r < 4; ++r) {
      const float e = __builtin_exp2f(sa[tz][r] * C);
      sa[tz][r] = e;
      s += e;
    }
  s += __shfl_xor(s, 16, 64);
  s += __shfl_xor(s, 32, 64);
  // inv folds BOTH the softmax normalization and the Q x32 carried scale
  const float inv = 1.0f / (s * FP8_SCALE);

  __syncthreads();   // barrier B: Q visible to all; all waves done reading K -> P may overwrite

  // P bf16 over the K region (base 9984, stride 208 B)
  #pragma unroll
  for (int tz = 0; tz < 6; ++tz) {
    const float p0 = sa[tz][0] * inv;
    const float p1 = sa[tz][1] * inv;
    const float p2 = sa[tz][2] * inv;
    const float p3 = sa[tz][3] * inv;
    *(uint2*)&KQ[9984 + xrow * 208 + tz*32 + lq*8] = uint2{pack2bf(p0, p1), pack2bf(p2, p3)};
  }

  // PV D[z'][x]: A = Q z'-tiles (fp8 LDS -> bf16 regs, x32), B = P x-rows (own-wave LDS)
  bf16x8 bp[3];
  #pragma unroll
  for (int ks = 0; ks < 3; ++ks)
    bp[ks] = *(const bf16x8*)&KQ[9984 + xrow * 208 + ks*64 + lq*16];
  f32x4 oa[6];
  #pragma unroll
  for (int i = 0; i < 6; ++i) oa[i] = zero4;
  #pragma unroll
  for (int tz = 0; tz < 6; ++tz)
    #pragma unroll
    for (int ks = 0; ks < 3; ++ks) {
      const uint2 qraw = *(const uint2*)&KQ[(tz*16 + lcol) * 104 + ks*32 + lq*8];
      const uint2 a0 = fp8x4_to_bf16x4_ns(qraw.x);
      const uint2 a1 = fp8x4_to_bf16x4_ns(qraw.y);
      const bf16x8 aq = __builtin_bit_cast(bf16x8, uint4{a0.x, a0.y, a1.x, a1.y});
      oa[tz] = __builtin_amdgcn_mfma_f32_16x16x32_bf16(aq, bp[ks], oa[tz], 0, 0, 0);
    }

  // store O[x][z'] bf16; 4 consecutive z' per lane -> dwordx2
  uint16_t* __restrict__ dst = Obuf + (size_t)(b * 512 + hc) * VST;
  #pragma unroll
  for (int tz = 0; tz < 6; ++tz)
    *(uint2*)(dst + (size_t)xrow * 96 + tz*16 + lq*4) =
      uint2{pack2bf(oa[tz][0], oa[tz][1]), pack2bf(oa[tz][2], oa[tz][3])};
}

// ---------------- Kernel 3 (MFMA GEMM): R6-exact ----------------
__global__ __launch_bounds__(512, 4) void out_proj_kernel(
    const uint16_t* __restrict__ Obuf, const uint16_t* __restrict__ wob,
    const float* __restrict__ b_out, float* __restrict__ out)
{
  __shared__ __align__(16) uint32_t As2[2][32 * RSTD];
  __shared__ __align__(16) uint16_t Wl[2][64 * WST];

  const int t    = threadIdx.x;
  const int blk  = blockIdx.x;          // 576 = 4b * 144 nt
  const int nt   = blk % 144;
  const int b    = blk / 144;
  const int n0   = nt * 64;
  const int L    = t & 63;
  const int w    = t >> 6;              // 0..7
  const int wo   = w >> 1;              // o-tile 0..3
  const int wp   = w & 1;               // p-pair 0..1
  const int lcol = L & 15;
  const int lq   = L >> 4;
  const int kp_g = t >> 4;              // 0..31: all packed-k rows, one per thread
  const int seg  = t & 15;              // 16 segs x 2 dwords

  const uint16_t* __restrict__ ab = Obuf + (size_t)b * 512 * VST;

  uint2 pa[2];
  uint2 pwb[2];

  auto load_chunk = [&](int k0) {
    const int ke = k0 + 2*kp_g, ko = ke + 1;
    const int pe = ((ke & 7) << 6) | (ke >> 3);
    const int po = ((ko & 7) << 6) | (ko >> 3);
    pa[0] = *(const uint2*)(ab + (size_t)pe * VST + n0 + seg * 4);
    pa[1] = *(const uint2*)(ab + (size_t)po * VST + n0 + seg * 4);
    #pragma unroll
    for (int i = 0; i < 2; ++i) {
      const int idx = t + i * 512;
      pwb[i] = *(const uint2*)(wob + (size_t)(idx >> 4) * 512 + k0 + (idx & 15) * 4);
    }
  };

  auto store_chunk = [&](int buf) {
    {
      const uint2 a = pa[0], bb = pa[1];
      uint4 d;
      d.x = (a.x & 0xffffu) | (bb.x << 16);
      d.y = (a.x >> 16)     | (bb.x & 0xffff0000u);
      d.z = (a.y & 0xffffu) | (bb.y << 16);
      d.w = (a.y >> 16)     | (bb.y & 0xffff0000u);
      *(uint4*)&As2[buf][kp_g * RSTD + seg * 4] = d;
    }
    #pragma unroll
    for (int i = 0; i < 2; ++i) {
      const int idx = t + i * 512;
      *(uint2*)&Wl[buf][(idx >> 4) * WST + (idx & 15) * 4] = pwb[i];
    }
  };

  f32x4 acc[2];
  const f32x4 zero4 = {0.f, 0.f, 0.f, 0.f};
  #pragma unroll
  for (int tm = 0; tm < 2; ++tm) acc[tm] = zero4;

  load_chunk(0);

  for (int c = 0; c < 8; ++c) {
    const int buf = c & 1;
    store_chunk(buf);
    if (c < 7) load_chunk((c + 1) * 64);
    __syncthreads();
    #pragma unroll
    for (int ks = 0; ks < 2; ++ks) {
      const bf16x8 af = *(const bf16x8*)&Wl[buf][(wo*16 + lcol) * WST + ks*32 + lq*8];
      #pragma unroll
      for (int tm = 0; tm < 2; ++tm) {
        u32x4 bb;
        #pragma unroll
        for (int jj = 0; jj < 4; ++jj)
          bb[jj] = As2[buf][(ks*16 + lq*4 + jj) * RSTD + (wp*2 + tm)*16 + lcol];
        const bf16x8 bfr = __builtin_bit_cast(bf16x8, bb);
        acc[tm] = __builtin_amdgcn_mfma_f32_16x16x32_bf16(af, bfr, acc[tm], 0, 0, 0);
      }
    }
  }

  #pragma unroll
  for (int tm = 0; tm < 2; ++tm) {
    const int p = n0 + (wp*2 + tm)*16 + lcol;
    #pragma unroll
    for (int r = 0; r < 4; ++r) {
      const int o = wo*16 + lq*4 + r;
      out[(size_t)(b * 64 + o) * TSS + p] = acc[tm][r] + b_out[o];
    }
  }
}

extern "C" void kernel_launch(void* const* d_in, const int* in_sizes, int n_in,
                              void* d_out, int out_size, void* d_ws, size_t ws_size,
                              hipStream_t stream) {
  const float* x     = (const float*)d_in[0];
  const float* w_vkq = (const float*)d_in[1];
  const float* b_vkq = (const float*)d_in[2];
  const float* w_out = (const float*)d_in[3];
  const float* b_out = (const float*)d_in[4];
  float* out = (float*)d_out;

  uint16_t* Obuf = (uint16_t*)d_ws;                         // 2048*9344*2 = 38.3 MB (bf16 O)
  uint8_t*  Vr   = (uint8_t*)(Obuf + (size_t)2048 * VST);   // 3 fp8 regions, 19.4 MB each
  uint8_t*  Qr   = Vr + (size_t)2048 * VSF;
  uint8_t*  Kr   = Qr + (size_t)2048 * VSF;
  uint16_t* wbf  = (uint16_t*)(Kr + (size_t)2048 * VSF);    // 196 KB bf16 W_vkq (x32 pre-scaled)
  uint16_t* wob  = wbf + (size_t)98304;                     // 64 KB bf16 w_out (unscaled)

  wcvt_kernel<<<dim3(128), dim3(256), 0, stream>>>(w_vkq, w_out, wbf, wob);
  proj_kernel<<<dim3(2304), dim3(256), 0, stream>>>(x, wbf, b_vkq, Vr, Qr, Kr);
  // TIMING PROBE: attn launched twice (idempotent — identical inputs -> identical Obuf).
  // dur_us_this_round - 120.5 = T_attn. Expected regression; buys per-kernel attribution.
  attn_kernel<<<dim3(2048), dim3(384), 0, stream>>>(Vr, Qr, Kr, Obuf);
  attn_kernel<<<dim3(2048), dim3(384), 0, stream>>>(Vr, Qr, Kr, Obuf);
  out_proj_kernel<<<dim3(576), dim3(512), 0, stream>>>(Obuf, wob, b_out, out);
}

// Round 9
// 140.026 us; speedup vs baseline: 1.0178x; 1.0178x over previous
//
#include <hip/hip_runtime.h>
#include <cstdint>
#include <cstddef>

typedef float f32x4 __attribute__((ext_vector_type(4)));
typedef float f32x2 __attribute__((ext_vector_type(2)));
typedef __bf16 bf16x8 __attribute__((ext_vector_type(8)));
typedef __bf16 bf16x2 __attribute__((ext_vector_type(2)));
typedef uint32_t u32x4 __attribute__((ext_vector_type(4)));

#define TSS 9216
#define VST 9344  // O-plane row stride (bf16 elements)
#define VSF 9472  // fp8 plane stride (bytes), 16B-multiple
#define XST 72    // proj X^T LDS row stride (bf16)
#define WST 72    // out_proj W-chunk row stride (bf16)
#define RSTD 68   // out_proj A-chunk row stride in DWORDS
#define EPS 68    // proj epilogue LDS row stride (BYTES): 17 dwords, conflict-free transpose

#define FP8_SCALE 32.0f   // V,Q,K stored as fp8 of 32*value (kills denormal flush)

__device__ __forceinline__ uint32_t pack2bf(float a, float b) {
  bf16x2 v = { (__bf16)a, (__bf16)b };   // native v_cvt_pk_bf16_f32 (RNE)
  return __builtin_bit_cast(uint32_t, v);
}
__device__ __forceinline__ uint32_t pack4fp8(float a, float b, float c, float d) {
  uint32_t r = __builtin_amdgcn_cvt_pk_fp8_f32(a, b, 0, false);
  return (uint32_t)__builtin_amdgcn_cvt_pk_fp8_f32(c, d, (int)r, true);
}
// 4 packed fp8 -> 4 bf16, NO scale (x32 carried through; folded into softmax inv)
__device__ __forceinline__ uint2 fp8x4_to_bf16x4_ns(uint32_t v) {
  const f32x2 lo = __builtin_amdgcn_cvt_pk_f32_fp8((int)v, false);
  const f32x2 hi = __builtin_amdgcn_cvt_pk_f32_fp8((int)v, true);
  return uint2{pack2bf(lo[0], lo[1]), pack2bf(hi[0], hi[1])};
}

// ---------------- Kernel 0: one-time W pre-conversion ----------------
__global__ __launch_bounds__(256, 8) void wcvt_kernel(
    const float* __restrict__ w_vkq, const float* __restrict__ w_out,
    uint16_t* __restrict__ wbf, uint16_t* __restrict__ wob)
{
  const int i = blockIdx.x * 256 + threadIdx.x;
  if (i < 24576) {          // 24576 float4 = 1536*64 floats of w_vkq
    const float4 v = ((const float4*)w_vkq)[i];
    ((uint2*)wbf)[i] = uint2{pack2bf(v.x * FP8_SCALE, v.y * FP8_SCALE),
                             pack2bf(v.z * FP8_SCALE, v.w * FP8_SCALE)};
  } else {                  // 8192 float4 = 64*512 floats of w_out
    const int j = i - 24576;
    const float4 v = ((const float4*)w_out)[j];
    ((uint2*)wob)[j] = uint2{pack2bf(v.x, v.y), pack2bf(v.z, v.w)};
  }
}

// ---------------- Kernel 1: projection (R4-exact). Launched TWICE this round as an
// idempotent timing probe: dur_us = 120.5 + T_proj. -----------------------------------------
__global__ __launch_bounds__(256, 4) void proj_kernel(
    const float* __restrict__ x, const uint16_t* __restrict__ wbf,
    const float* __restrict__ b_vkq,
    uint8_t* __restrict__ Vr, uint8_t* __restrict__ Qr, uint8_t* __restrict__ Kr)
{
  __shared__ __align__(16) uint16_t Bt[64 * XST];      // X^T tile [p][c] bf16 (9.2 KB)
  __shared__ __align__(16) uint8_t  Ep[4][16 * EPS];   // per-wave transpose scratch (4.3 KB)

  const int t   = threadIdx.x;
  const int blk = blockIdx.x;        // 2304; XCD-grouped: oq in bits [3:4], low 3 bits = bn%8
  const int oq  = (blk >> 3) & 3;
  const int bn  = (blk & 7) | ((blk >> 5) << 3);
  const int nt  = bn % 144;
  const int b   = bn / 144;
  const int n0  = nt * 64;

  {
    const float* __restrict__ xb = x + (size_t)b * 64 * TSS + n0;
    const int p  = t & 63;
    const int c0 = (t >> 6) * 16;
    float v[16];
    #pragma unroll
    for (int i = 0; i < 16; ++i) v[i] = xb[(size_t)(c0 + i) * TSS + p];
    #pragma unroll
    for (int h = 0; h < 2; ++h)
      *(uint4*)&Bt[p * XST + c0 + h*8] =
        uint4{pack2bf(v[h*8+0], v[h*8+1]), pack2bf(v[h*8+2], v[h*8+3]),
              pack2bf(v[h*8+4], v[h*8+5]), pack2bf(v[h*8+6], v[h*8+7])};
  }
  __syncthreads();

  const int L    = t & 63;
  const int w    = t >> 6;
  const int lcol = L & 15;
  const int lq   = L >> 4;

  bf16x8 af[4][2];   // A = X^T, m = p (4 tiles of 16) — invariant all 6 o-tiles
  #pragma unroll
  for (int tm = 0; tm < 4; ++tm)
    #pragma unroll
    for (int ks = 0; ks < 2; ++ks)
      af[tm][ks] = *(const bf16x8*)&Bt[(tm*16 + lcol) * XST + ks*32 + lq*8];

  const int obase = oq * 384 + w * 96;   // wave's 6 o-tiles

  bf16x8 bw[3][2];
  float  bias_r[3];
  #pragma unroll
  for (int pre = 0; pre < 3; ++pre) {
    const int o = obase + pre*16 + lcol;
    #pragma unroll
    for (int ks = 0; ks < 2; ++ks)
      bw[pre][ks] = *(const bf16x8*)(wbf + (size_t)o * 64 + ks*32 + lq*8);
    bias_r[pre] = b_vkq[o] * FP8_SCALE;
  }

  uint8_t* __restrict__ ep = Ep[w];

  #pragma unroll
  for (int ot = 0; ot < 6; ++ot) {
    const int s3   = ot % 3;
    const float bias = bias_r[s3];
    f32x4 acc[4];
    #pragma unroll
    for (int tm = 0; tm < 4; ++tm) acc[tm] = f32x4{bias, bias, bias, bias};
    #pragma unroll
    for (int tm = 0; tm < 4; ++tm)
      #pragma unroll
      for (int ks = 0; ks < 2; ++ks)
        acc[tm] = __builtin_amdgcn_mfma_f32_16x16x32_bf16(af[tm][ks], bw[s3][ks], acc[tm], 0, 0, 0);
    if (ot < 3) {
      const int on = obase + (ot + 3)*16 + lcol;
      #pragma unroll
      for (int ks = 0; ks < 2; ++ks)
        bw[s3][ks] = *(const bf16x8*)(wbf + (size_t)on * 64 + ks*32 + lq*8);
      bias_r[s3] = b_vkq[on] * FP8_SCALE;
    }
    // transpose D[p][o] -> [o][p] through wave-private LDS (in-order per wave, no barrier)
    #pragma unroll
    for (int tm = 0; tm < 4; ++tm)
      *(uint32_t*)&ep[lcol * EPS + tm*16 + lq*4] =
        pack4fp8(acc[tm][0], acc[tm][1], acc[tm][2], acc[tm][3]);

    const int o_t  = obase + ot * 16;
    const int sreg = o_t >> 9;   // 0=V 1=Q 2=K (16-tile never straddles a 512 boundary)
    uint8_t* __restrict__ reg = (sreg == 0) ? Vr : ((sreg == 1) ? Qr : Kr);
    const size_t rb = (size_t)(b * 512 + (o_t & 511)) * VSF + n0;
    #pragma unroll
    for (int s = 0; s < 4; ++s) {
      const int orow = s*4 + lq;
      const uint32_t d = *(const uint32_t*)&ep[orow * EPS + lcol*4];
      *(uint32_t*)(reg + rb + (size_t)orow * VSF + lcol*4) = d;   // 4 full 64-B rows / instr
    }
  }
}

// ---------------- Kernel 2: attention (R7-exact, single launch again; T_attn ~= 22 us) ------
__global__ __launch_bounds__(384, 4) void attn_kernel(
    const uint8_t* __restrict__ Vr, const uint8_t* __restrict__ Qr,
    const uint8_t* __restrict__ Kr, uint16_t* __restrict__ Obuf)
{
  __shared__ __align__(16) uint8_t KQ[29952];

  const int t   = threadIdx.x;
  const int blk = blockIdx.x;
  const int b   = blk >> 9;
  const int hc  = blk & 511;
  const size_t pb8 = (size_t)(b * 512 + hc) * VSF;
  const uint8_t* __restrict__ vplane = Vr + pb8;

  const uint4* __restrict__ sk = (const uint4*)(Kr + pb8);
  const uint4* __restrict__ sq = (const uint4*)(Qr + pb8);

  // stage K now; issue Q loads now but hold in regs (LDS write deferred past QK^T)
  uint4 q0, q1;
  const int r0 = t / 6, s0 = t % 6;
  int r1 = 0, s1 = 0;
  q0 = sq[t];
  *(uint4*)&KQ[9984 + r0 * 104 + s0 * 16] = sk[t];
  if (t < 192) {
    const int g = t + 384;
    r1 = g / 6; s1 = g % 6;
    q1 = sq[g];
    *(uint4*)&KQ[9984 + r1 * 104 + s1 * 16] = sk[g];
  }

  const int L    = t & 63;
  const int w    = t / 64;
  const int lcol = L & 15;
  const int lq   = L >> 4;
  const int xrow = 16 * w + lcol;
  // scores carry FP8_SCALE^2 = 1024x; fold into exp2 constant
  const float C  = 1.44269504088896f / (9216.0f * (FP8_SCALE * FP8_SCALE));
  const f32x4 zero4 = {0.f, 0.f, 0.f, 0.f};

  // V B-frags straight from global (own rows only): 8 consecutive fp8 = one b64
  long bv[3];
  #pragma unroll
  for (int ks = 0; ks < 3; ++ks)
    bv[ks] = *(const long*)(vplane + (size_t)xrow * 96 + ks*32 + lq*8);

  __syncthreads();   // barrier A: K staged (Q loads drain here too, but writes are deferred)

  // scores D[z][x]: A = K z-tiles, B = V x-rows (fp8 MFMA)
  f32x4 sa[6];
  #pragma unroll
  for (int i = 0; i < 6; ++i) sa[i] = zero4;
  #pragma unroll
  for (int tz = 0; tz < 6; ++tz)
    #pragma unroll
    for (int ks = 0; ks < 3; ++ks) {
      const long ak = *(const long*)&KQ[9984 + (tz*16 + lcol) * 104 + ks*32 + lq*8];
      sa[tz] = __builtin_amdgcn_mfma_f32_16x16x32_fp8_fp8(ak, bv[ks], sa[tz], 0, 0, 0);
    }

  // write Q (fp8) to its own LDS region — races nothing (region unused until after
  // barrier B); ds-write latency hides under the softmax VALU below
  *(uint4*)&KQ[r0 * 104 + s0 * 16] = q0;
  if (t < 192)
    *(uint4*)&KQ[r1 * 104 + s1 * 16] = q1;

  // softmax over z (|s_true| <= 0.007 -> max-subtraction safely dropped)
  float s = 0.f;
  #pragma unroll
  for (int tz = 0; tz < 6; ++tz)
    #pragma unroll
    for (int r = 0; r < 4; ++r) {
      const float e = __builtin_exp2f(sa[tz][r] * C);
      sa[tz][r] = e;
      s += e;
    }
  s += __shfl_xor(s, 16, 64);
  s += __shfl_xor(s, 32, 64);
  // inv folds BOTH the softmax normalization and the Q x32 carried scale
  const float inv = 1.0f / (s * FP8_SCALE);

  __syncthreads();   // barrier B: Q visible to all; all waves done reading K -> P may overwrite

  // P bf16 over the K region (base 9984, stride 208 B)
  #pragma unroll
  for (int tz = 0; tz < 6; ++tz) {
    const float p0 = sa[tz][0] * inv;
    const float p1 = sa[tz][1] * inv;
    const float p2 = sa[tz][2] * inv;
    const float p3 = sa[tz][3] * inv;
    *(uint2*)&KQ[9984 + xrow * 208 + tz*32 + lq*8] = uint2{pack2bf(p0, p1), pack2bf(p2, p3)};
  }

  // PV D[z'][x]: A = Q z'-tiles (fp8 LDS -> bf16 regs, x32), B = P x-rows (own-wave LDS)
  bf16x8 bp[3];
  #pragma unroll
  for (int ks = 0; ks < 3; ++ks)
    bp[ks] = *(const bf16x8*)&KQ[9984 + xrow * 208 + ks*64 + lq*16];
  f32x4 oa[6];
  #pragma unroll
  for (int i = 0; i < 6; ++i) oa[i] = zero4;
  #pragma unroll
  for (int tz = 0; tz < 6; ++tz)
    #pragma unroll
    for (int ks = 0; ks < 3; ++ks) {
      const uint2 qraw = *(const uint2*)&KQ[(tz*16 + lcol) * 104 + ks*32 + lq*8];
      const uint2 a0 = fp8x4_to_bf16x4_ns(qraw.x);
      const uint2 a1 = fp8x4_to_bf16x4_ns(qraw.y);
      const bf16x8 aq = __builtin_bit_cast(bf16x8, uint4{a0.x, a0.y, a1.x, a1.y});
      oa[tz] = __builtin_amdgcn_mfma_f32_16x16x32_bf16(aq, bp[ks], oa[tz], 0, 0, 0);
    }

  // store O[x][z'] bf16; 4 consecutive z' per lane -> dwordx2
  uint16_t* __restrict__ dst = Obuf + (size_t)(b * 512 + hc) * VST;
  #pragma unroll
  for (int tz = 0; tz < 6; ++tz)
    *(uint2*)(dst + (size_t)xrow * 96 + tz*16 + lq*4) =
      uint2{pack2bf(oa[tz][0], oa[tz][1]), pack2bf(oa[tz][2], oa[tz][3])};
}

// ---------------- Kernel 3 (MFMA GEMM): R6-exact ----------------
__global__ __launch_bounds__(512, 4) void out_proj_kernel(
    const uint16_t* __restrict__ Obuf, const uint16_t* __restrict__ wob,
    const float* __restrict__ b_out, float* __restrict__ out)
{
  __shared__ __align__(16) uint32_t As2[2][32 * RSTD];
  __shared__ __align__(16) uint16_t Wl[2][64 * WST];

  const int t    = threadIdx.x;
  const int blk  = blockIdx.x;          // 576 = 4b * 144 nt
  const int nt   = blk % 144;
  const int b    = blk / 144;
  const int n0   = nt * 64;
  const int L    = t & 63;
  const int w    = t >> 6;              // 0..7
  const int wo   = w >> 1;              // o-tile 0..3
  const int wp   = w & 1;               // p-pair 0..1
  const int lcol = L & 15;
  const int lq   = L >> 4;
  const int kp_g = t >> 4;              // 0..31: all packed-k rows, one per thread
  const int seg  = t & 15;              // 16 segs x 2 dwords

  const uint16_t* __restrict__ ab = Obuf + (size_t)b * 512 * VST;

  uint2 pa[2];
  uint2 pwb[2];

  auto load_chunk = [&](int k0) {
    const int ke = k0 + 2*kp_g, ko = ke + 1;
    const int pe = ((ke & 7) << 6) | (ke >> 3);
    const int po = ((ko & 7) << 6) | (ko >> 3);
    pa[0] = *(const uint2*)(ab + (size_t)pe * VST + n0 + seg * 4);
    pa[1] = *(const uint2*)(ab + (size_t)po * VST + n0 + seg * 4);
    #pragma unroll
    for (int i = 0; i < 2; ++i) {
      const int idx = t + i * 512;
      pwb[i] = *(const uint2*)(wob + (size_t)(idx >> 4) * 512 + k0 + (idx & 15) * 4);
    }
  };

  auto store_chunk = [&](int buf) {
    {
      const uint2 a = pa[0], bb = pa[1];
      uint4 d;
      d.x = (a.x & 0xffffu) | (bb.x << 16);
      d.y = (a.x >> 16)     | (bb.x & 0xffff0000u);
      d.z = (a.y & 0xffffu) | (bb.y << 16);
      d.w = (a.y >> 16)     | (bb.y & 0xffff0000u);
      *(uint4*)&As2[buf][kp_g * RSTD + seg * 4] = d;
    }
    #pragma unroll
    for (int i = 0; i < 2; ++i) {
      const int idx = t + i * 512;
      *(uint2*)&Wl[buf][(idx >> 4) * WST + (idx & 15) * 4] = pwb[i];
    }
  };

  f32x4 acc[2];
  const f32x4 zero4 = {0.f, 0.f, 0.f, 0.f};
  #pragma unroll
  for (int tm = 0; tm < 2; ++tm) acc[tm] = zero4;

  load_chunk(0);

  for (int c = 0; c < 8; ++c) {
    const int buf = c & 1;
    store_chunk(buf);
    if (c < 7) load_chunk((c + 1) * 64);
    __syncthreads();
    #pragma unroll
    for (int ks = 0; ks < 2; ++ks) {
      const bf16x8 af = *(const bf16x8*)&Wl[buf][(wo*16 + lcol) * WST + ks*32 + lq*8];
      #pragma unroll
      for (int tm = 0; tm < 2; ++tm) {
        u32x4 bb;
        #pragma unroll
        for (int jj = 0; jj < 4; ++jj)
          bb[jj] = As2[buf][(ks*16 + lq*4 + jj) * RSTD + (wp*2 + tm)*16 + lcol];
        const bf16x8 bfr = __builtin_bit_cast(bf16x8, bb);
        acc[tm] = __builtin_amdgcn_mfma_f32_16x16x32_bf16(af, bfr, acc[tm], 0, 0, 0);
      }
    }
  }

  #pragma unroll
  for (int tm = 0; tm < 2; ++tm) {
    const int p = n0 + (wp*2 + tm)*16 + lcol;
    #pragma unroll
    for (int r = 0; r < 4; ++r) {
      const int o = wo*16 + lq*4 + r;
      out[(size_t)(b * 64 + o) * TSS + p] = acc[tm][r] + b_out[o];
    }
  }
}

extern "C" void kernel_launch(void* const* d_in, const int* in_sizes, int n_in,
                              void* d_out, int out_size, void* d_ws, size_t ws_size,
                              hipStream_t stream) {
  const float* x     = (const float*)d_in[0];
  const float* w_vkq = (const float*)d_in[1];
  const float* b_vkq = (const float*)d_in[2];
  const float* w_out = (const float*)d_in[3];
  const float* b_out = (const float*)d_in[4];
  float* out = (float*)d_out;

  uint16_t* Obuf = (uint16_t*)d_ws;                         // 2048*9344*2 = 38.3 MB (bf16 O)
  uint8_t*  Vr   = (uint8_t*)(Obuf + (size_t)2048 * VST);   // 3 fp8 regions, 19.4 MB each
  uint8_t*  Qr   = Vr + (size_t)2048 * VSF;
  uint8_t*  Kr   = Qr + (size_t)2048 * VSF;
  uint16_t* wbf  = (uint16_t*)(Kr + (size_t)2048 * VSF);    // 196 KB bf16 W_vkq (x32 pre-scaled)
  uint16_t* wob  = wbf + (size_t)98304;                     // 64 KB bf16 w_out (unscaled)

  wcvt_kernel<<<dim3(128), dim3(256), 0, stream>>>(w_vkq, w_out, wbf, wob);
  // TIMING PROBE: proj launched twice (idempotent — identical inputs -> identical V/Q/K).
  // dur_us_this_round - 120.5 = T_proj. Attn back to single launch (T_attn ~= 22 us, R8).
  proj_kernel<<<dim3(2304), dim3(256), 0, stream>>>(x, wbf, b_vkq, Vr, Qr, Kr);
  proj_kernel<<<dim3(2304), dim3(256), 0, stream>>>(x, wbf, b_vkq, Vr, Qr, Kr);
  attn_kernel<<<dim3(2048), dim3(384), 0, stream>>>(Vr, Qr, Kr, Obuf);
  out_proj_kernel<<<dim3(576), dim3(512), 0, stream>>>(Obuf, wob, b_out, out);
}

// Round 10
// 131.700 us; speedup vs baseline: 1.0822x; 1.0632x over previous
//
#include <hip/hip_runtime.h>
#include <cstdint>
#include <cstddef>

typedef float f32x4 __attribute__((ext_vector_type(4)));
typedef float f32x2 __attribute__((ext_vector_type(2)));
typedef __bf16 bf16x8 __attribute__((ext_vector_type(8)));
typedef __bf16 bf16x2 __attribute__((ext_vector_type(2)));
typedef uint32_t u32x4 __attribute__((ext_vector_type(4)));

#define TSS 9216
#define VST 9344  // O-plane row stride (bf16 elements)
#define VSF 9472  // fp8 plane stride (bytes), 16B-multiple
#define XST 72    // proj X^T LDS row stride (bf16)
#define WST 72    // out_proj W-chunk row stride (bf16)
#define RSTD 68   // out_proj A-chunk row stride in DWORDS
#define EPS 68    // proj epilogue LDS row stride (BYTES): 17 dwords, conflict-free transpose

#define FP8_SCALE 32.0f   // V,Q,K stored as fp8 of 32*value (kills denormal flush)

__device__ __forceinline__ uint32_t pack2bf(float a, float b) {
  bf16x2 v = { (__bf16)a, (__bf16)b };   // native v_cvt_pk_bf16_f32 (RNE)
  return __builtin_bit_cast(uint32_t, v);
}
__device__ __forceinline__ uint32_t pack4fp8(float a, float b, float c, float d) {
  uint32_t r = __builtin_amdgcn_cvt_pk_fp8_f32(a, b, 0, false);
  return (uint32_t)__builtin_amdgcn_cvt_pk_fp8_f32(c, d, (int)r, true);
}
// 4 packed fp8 -> 4 bf16, NO scale (x32 carried through; folded into softmax inv)
__device__ __forceinline__ uint2 fp8x4_to_bf16x4_ns(uint32_t v) {
  const f32x2 lo = __builtin_amdgcn_cvt_pk_f32_fp8((int)v, false);
  const f32x2 hi = __builtin_amdgcn_cvt_pk_f32_fp8((int)v, true);
  return uint2{pack2bf(lo[0], lo[1]), pack2bf(hi[0], hi[1])};
}

// ---------------- Kernel 0: one-time W pre-conversion ----------------
__global__ __launch_bounds__(256, 8) void wcvt_kernel(
    const float* __restrict__ w_vkq, const float* __restrict__ w_out,
    uint16_t* __restrict__ wbf, uint16_t* __restrict__ wob)
{
  const int i = blockIdx.x * 256 + threadIdx.x;
  if (i < 24576) {          // 24576 float4 = 1536*64 floats of w_vkq
    const float4 v = ((const float4*)w_vkq)[i];
    ((uint2*)wbf)[i] = uint2{pack2bf(v.x * FP8_SCALE, v.y * FP8_SCALE),
                             pack2bf(v.z * FP8_SCALE, v.w * FP8_SCALE)};
  } else {                  // 8192 float4 = 64*512 floats of w_out
    const int j = i - 24576;
    const float4 v = ((const float4*)w_out)[j];
    ((uint2*)wob)[j] = uint2{pack2bf(v.x, v.y), pack2bf(v.z, v.w)};
  }
}

// ---------------- Kernel 1: projection (R4-exact; T_proj ~= 19.5 us, R9 probe) --------------
__global__ __launch_bounds__(256, 4) void proj_kernel(
    const float* __restrict__ x, const uint16_t* __restrict__ wbf,
    const float* __restrict__ b_vkq,
    uint8_t* __restrict__ Vr, uint8_t* __restrict__ Qr, uint8_t* __restrict__ Kr)
{
  __shared__ __align__(16) uint16_t Bt[64 * XST];      // X^T tile [p][c] bf16 (9.2 KB)
  __shared__ __align__(16) uint8_t  Ep[4][16 * EPS];   // per-wave transpose scratch (4.3 KB)

  const int t   = threadIdx.x;
  const int blk = blockIdx.x;        // 2304; XCD-grouped: oq in bits [3:4], low 3 bits = bn%8
  const int oq  = (blk >> 3) & 3;
  const int bn  = (blk & 7) | ((blk >> 5) << 3);
  const int nt  = bn % 144;
  const int b   = bn / 144;
  const int n0  = nt * 64;

  {
    const float* __restrict__ xb = x + (size_t)b * 64 * TSS + n0;
    const int p  = t & 63;
    const int c0 = (t >> 6) * 16;
    float v[16];
    #pragma unroll
    for (int i = 0; i < 16; ++i) v[i] = xb[(size_t)(c0 + i) * TSS + p];
    #pragma unroll
    for (int h = 0; h < 2; ++h)
      *(uint4*)&Bt[p * XST + c0 + h*8] =
        uint4{pack2bf(v[h*8+0], v[h*8+1]), pack2bf(v[h*8+2], v[h*8+3]),
              pack2bf(v[h*8+4], v[h*8+5]), pack2bf(v[h*8+6], v[h*8+7])};
  }
  __syncthreads();

  const int L    = t & 63;
  const int w    = t >> 6;
  const int lcol = L & 15;
  const int lq   = L >> 4;

  bf16x8 af[4][2];   // A = X^T, m = p (4 tiles of 16) — invariant all 6 o-tiles
  #pragma unroll
  for (int tm = 0; tm < 4; ++tm)
    #pragma unroll
    for (int ks = 0; ks < 2; ++ks)
      af[tm][ks] = *(const bf16x8*)&Bt[(tm*16 + lcol) * XST + ks*32 + lq*8];

  const int obase = oq * 384 + w * 96;   // wave's 6 o-tiles

  bf16x8 bw[3][2];
  float  bias_r[3];
  #pragma unroll
  for (int pre = 0; pre < 3; ++pre) {
    const int o = obase + pre*16 + lcol;
    #pragma unroll
    for (int ks = 0; ks < 2; ++ks)
      bw[pre][ks] = *(const bf16x8*)(wbf + (size_t)o * 64 + ks*32 + lq*8);
    bias_r[pre] = b_vkq[o] * FP8_SCALE;
  }

  uint8_t* __restrict__ ep = Ep[w];

  #pragma unroll
  for (int ot = 0; ot < 6; ++ot) {
    const int s3   = ot % 3;
    const float bias = bias_r[s3];
    f32x4 acc[4];
    #pragma unroll
    for (int tm = 0; tm < 4; ++tm) acc[tm] = f32x4{bias, bias, bias, bias};
    #pragma unroll
    for (int tm = 0; tm < 4; ++tm)
      #pragma unroll
      for (int ks = 0; ks < 2; ++ks)
        acc[tm] = __builtin_amdgcn_mfma_f32_16x16x32_bf16(af[tm][ks], bw[s3][ks], acc[tm], 0, 0, 0);
    if (ot < 3) {
      const int on = obase + (ot + 3)*16 + lcol;
      #pragma unroll
      for (int ks = 0; ks < 2; ++ks)
        bw[s3][ks] = *(const bf16x8*)(wbf + (size_t)on * 64 + ks*32 + lq*8);
      bias_r[s3] = b_vkq[on] * FP8_SCALE;
    }
    // transpose D[p][o] -> [o][p] through wave-private LDS (in-order per wave, no barrier)
    #pragma unroll
    for (int tm = 0; tm < 4; ++tm)
      *(uint32_t*)&ep[lcol * EPS + tm*16 + lq*4] =
        pack4fp8(acc[tm][0], acc[tm][1], acc[tm][2], acc[tm][3]);

    const int o_t  = obase + ot * 16;
    const int sreg = o_t >> 9;   // 0=V 1=Q 2=K (16-tile never straddles a 512 boundary)
    uint8_t* __restrict__ reg = (sreg == 0) ? Vr : ((sreg == 1) ? Qr : Kr);
    const size_t rb = (size_t)(b * 512 + (o_t & 511)) * VSF + n0;
    #pragma unroll
    for (int s = 0; s < 4; ++s) {
      const int orow = s*4 + lq;
      const uint32_t d = *(const uint32_t*)&ep[orow * EPS + lcol*4];
      *(uint32_t*)(reg + rb + (size_t)orow * VSF + lcol*4) = d;   // 4 full 64-B rows / instr
    }
  }
}

// ---------------- Kernel 2: attention (R7-exact; T_attn ~= 22 us, R8 probe) -----------------
__global__ __launch_bounds__(384, 4) void attn_kernel(
    const uint8_t* __restrict__ Vr, const uint8_t* __restrict__ Qr,
    const uint8_t* __restrict__ Kr, uint16_t* __restrict__ Obuf)
{
  __shared__ __align__(16) uint8_t KQ[29952];

  const int t   = threadIdx.x;
  const int blk = blockIdx.x;
  const int b   = blk >> 9;
  const int hc  = blk & 511;
  const size_t pb8 = (size_t)(b * 512 + hc) * VSF;
  const uint8_t* __restrict__ vplane = Vr + pb8;

  const uint4* __restrict__ sk = (const uint4*)(Kr + pb8);
  const uint4* __restrict__ sq = (const uint4*)(Qr + pb8);

  // stage K now; issue Q loads now but hold in regs (LDS write deferred past QK^T)
  uint4 q0, q1;
  const int r0 = t / 6, s0 = t % 6;
  int r1 = 0, s1 = 0;
  q0 = sq[t];
  *(uint4*)&KQ[9984 + r0 * 104 + s0 * 16] = sk[t];
  if (t < 192) {
    const int g = t + 384;
    r1 = g / 6; s1 = g % 6;
    q1 = sq[g];
    *(uint4*)&KQ[9984 + r1 * 104 + s1 * 16] = sk[g];
  }

  const int L    = t & 63;
  const int w    = t / 64;
  const int lcol = L & 15;
  const int lq   = L >> 4;
  const int xrow = 16 * w + lcol;
  // scores carry FP8_SCALE^2 = 1024x; fold into exp2 constant
  const float C  = 1.44269504088896f / (9216.0f * (FP8_SCALE * FP8_SCALE));
  const f32x4 zero4 = {0.f, 0.f, 0.f, 0.f};

  // V B-frags straight from global (own rows only): 8 consecutive fp8 = one b64
  long bv[3];
  #pragma unroll
  for (int ks = 0; ks < 3; ++ks)
    bv[ks] = *(const long*)(vplane + (size_t)xrow * 96 + ks*32 + lq*8);

  __syncthreads();   // barrier A: K staged (Q loads drain here too, but writes are deferred)

  // scores D[z][x]: A = K z-tiles, B = V x-rows (fp8 MFMA)
  f32x4 sa[6];
  #pragma unroll
  for (int i = 0; i < 6; ++i) sa[i] = zero4;
  #pragma unroll
  for (int tz = 0; tz < 6; ++tz)
    #pragma unroll
    for (int ks = 0; ks < 3; ++ks) {
      const long ak = *(const long*)&KQ[9984 + (tz*16 + lcol) * 104 + ks*32 + lq*8];
      sa[tz] = __builtin_amdgcn_mfma_f32_16x16x32_fp8_fp8(ak, bv[ks], sa[tz], 0, 0, 0);
    }

  // write Q (fp8) to its own LDS region — races nothing (region unused until after
  // barrier B); ds-write latency hides under the softmax VALU below
  *(uint4*)&KQ[r0 * 104 + s0 * 16] = q0;
  if (t < 192)
    *(uint4*)&KQ[r1 * 104 + s1 * 16] = q1;

  // softmax over z (|s_true| <= 0.007 -> max-subtraction safely dropped)
  float s = 0.f;
  #pragma unroll
  for (int tz = 0; tz < 6; ++tz)
    #pragma unroll
    for (int r = 0; r < 4; ++r) {
      const float e = __builtin_exp2f(sa[tz][r] * C);
      sa[tz][r] = e;
      s += e;
    }
  s += __shfl_xor(s, 16, 64);
  s += __shfl_xor(s, 32, 64);
  // inv folds BOTH the softmax normalization and the Q x32 carried scale
  const float inv = 1.0f / (s * FP8_SCALE);

  __syncthreads();   // barrier B: Q visible to all; all waves done reading K -> P may overwrite

  // P bf16 over the K region (base 9984, stride 208 B)
  #pragma unroll
  for (int tz = 0; tz < 6; ++tz) {
    const float p0 = sa[tz][0] * inv;
    const float p1 = sa[tz][1] * inv;
    const float p2 = sa[tz][2] * inv;
    const float p3 = sa[tz][3] * inv;
    *(uint2*)&KQ[9984 + xrow * 208 + tz*32 + lq*8] = uint2{pack2bf(p0, p1), pack2bf(p2, p3)};
  }

  // PV D[z'][x]: A = Q z'-tiles (fp8 LDS -> bf16 regs, x32), B = P x-rows (own-wave LDS)
  bf16x8 bp[3];
  #pragma unroll
  for (int ks = 0; ks < 3; ++ks)
    bp[ks] = *(const bf16x8*)&KQ[9984 + xrow * 208 + ks*64 + lq*16];
  f32x4 oa[6];
  #pragma unroll
  for (int i = 0; i < 6; ++i) oa[i] = zero4;
  #pragma unroll
  for (int tz = 0; tz < 6; ++tz)
    #pragma unroll
    for (int ks = 0; ks < 3; ++ks) {
      const uint2 qraw = *(const uint2*)&KQ[(tz*16 + lcol) * 104 + ks*32 + lq*8];
      const uint2 a0 = fp8x4_to_bf16x4_ns(qraw.x);
      const uint2 a1 = fp8x4_to_bf16x4_ns(qraw.y);
      const bf16x8 aq = __builtin_bit_cast(bf16x8, uint4{a0.x, a0.y, a1.x, a1.y});
      oa[tz] = __builtin_amdgcn_mfma_f32_16x16x32_bf16(aq, bp[ks], oa[tz], 0, 0, 0);
    }

  // store O[x][z'] bf16; 4 consecutive z' per lane -> dwordx2
  uint16_t* __restrict__ dst = Obuf + (size_t)(b * 512 + hc) * VST;
  #pragma unroll
  for (int tz = 0; tz < 6; ++tz)
    *(uint2*)(dst + (size_t)xrow * 96 + tz*16 + lq*4) =
      uint2{pack2bf(oa[tz][0], oa[tz][1]), pack2bf(oa[tz][2], oa[tz][3])};
}

// ---------------- Kernel 3 (MFMA GEMM): R6-exact. Launched TWICE this round as an
// idempotent timing probe: dur_us = 120.5 + T_outproj. --------------------------------------
__global__ __launch_bounds__(512, 4) void out_proj_kernel(
    const uint16_t* __restrict__ Obuf, const uint16_t* __restrict__ wob,
    const float* __restrict__ b_out, float* __restrict__ out)
{
  __shared__ __align__(16) uint32_t As2[2][32 * RSTD];
  __shared__ __align__(16) uint16_t Wl[2][64 * WST];

  const int t    = threadIdx.x;
  const int blk  = blockIdx.x;          // 576 = 4b * 144 nt
  const int nt   = blk % 144;
  const int b    = blk / 144;
  const int n0   = nt * 64;
  const int L    = t & 63;
  const int w    = t >> 6;              // 0..7
  const int wo   = w >> 1;              // o-tile 0..3
  const int wp   = w & 1;               // p-pair 0..1
  const int lcol = L & 15;
  const int lq   = L >> 4;
  const int kp_g = t >> 4;              // 0..31: all packed-k rows, one per thread
  const int seg  = t & 15;              // 16 segs x 2 dwords

  const uint16_t* __restrict__ ab = Obuf + (size_t)b * 512 * VST;

  uint2 pa[2];
  uint2 pwb[2];

  auto load_chunk = [&](int k0) {
    const int ke = k0 + 2*kp_g, ko = ke + 1;
    const int pe = ((ke & 7) << 6) | (ke >> 3);
    const int po = ((ko & 7) << 6) | (ko >> 3);
    pa[0] = *(const uint2*)(ab + (size_t)pe * VST + n0 + seg * 4);
    pa[1] = *(const uint2*)(ab + (size_t)po * VST + n0 + seg * 4);
    #pragma unroll
    for (int i = 0; i < 2; ++i) {
      const int idx = t + i * 512;
      pwb[i] = *(const uint2*)(wob + (size_t)(idx >> 4) * 512 + k0 + (idx & 15) * 4);
    }
  };

  auto store_chunk = [&](int buf) {
    {
      const uint2 a = pa[0], bb = pa[1];
      uint4 d;
      d.x = (a.x & 0xffffu) | (bb.x << 16);
      d.y = (a.x >> 16)     | (bb.x & 0xffff0000u);
      d.z = (a.y & 0xffffu) | (bb.y << 16);
      d.w = (a.y >> 16)     | (bb.y & 0xffff0000u);
      *(uint4*)&As2[buf][kp_g * RSTD + seg * 4] = d;
    }
    #pragma unroll
    for (int i = 0; i < 2; ++i) {
      const int idx = t + i * 512;
      *(uint2*)&Wl[buf][(idx >> 4) * WST + (idx & 15) * 4] = pwb[i];
    }
  };

  f32x4 acc[2];
  const f32x4 zero4 = {0.f, 0.f, 0.f, 0.f};
  #pragma unroll
  for (int tm = 0; tm < 2; ++tm) acc[tm] = zero4;

  load_chunk(0);

  for (int c = 0; c < 8; ++c) {
    const int buf = c & 1;
    store_chunk(buf);
    if (c < 7) load_chunk((c + 1) * 64);
    __syncthreads();
    #pragma unroll
    for (int ks = 0; ks < 2; ++ks) {
      const bf16x8 af = *(const bf16x8*)&Wl[buf][(wo*16 + lcol) * WST + ks*32 + lq*8];
      #pragma unroll
      for (int tm = 0; tm < 2; ++tm) {
        u32x4 bb;
        #pragma unroll
        for (int jj = 0; jj < 4; ++jj)
          bb[jj] = As2[buf][(ks*16 + lq*4 + jj) * RSTD + (wp*2 + tm)*16 + lcol];
        const bf16x8 bfr = __builtin_bit_cast(bf16x8, bb);
        acc[tm] = __builtin_amdgcn_mfma_f32_16x16x32_bf16(af, bfr, acc[tm], 0, 0, 0);
      }
    }
  }

  #pragma unroll
  for (int tm = 0; tm < 2; ++tm) {
    const int p = n0 + (wp*2 + tm)*16 + lcol;
    #pragma unroll
    for (int r = 0; r < 4; ++r) {
      const int o = wo*16 + lq*4 + r;
      out[(size_t)(b * 64 + o) * TSS + p] = acc[tm][r] + b_out[o];
    }
  }
}

extern "C" void kernel_launch(void* const* d_in, const int* in_sizes, int n_in,
                              void* d_out, int out_size, void* d_ws, size_t ws_size,
                              hipStream_t stream) {
  const float* x     = (const float*)d_in[0];
  const float* w_vkq = (const float*)d_in[1];
  const float* b_vkq = (const float*)d_in[2];
  const float* w_out = (const float*)d_in[3];
  const float* b_out = (const float*)d_in[4];
  float* out = (float*)d_out;

  uint16_t* Obuf = (uint16_t*)d_ws;                         // 2048*9344*2 = 38.3 MB (bf16 O)
  uint8_t*  Vr   = (uint8_t*)(Obuf + (size_t)2048 * VST);   // 3 fp8 regions, 19.4 MB each
  uint8_t*  Qr   = Vr + (size_t)2048 * VSF;
  uint8_t*  Kr   = Qr + (size_t)2048 * VSF;
  uint16_t* wbf  = (uint16_t*)(Kr + (size_t)2048 * VSF);    // 196 KB bf16 W_vkq (x32 pre-scaled)
  uint16_t* wob  = wbf + (size_t)98304;                     // 64 KB bf16 w_out (unscaled)

  wcvt_kernel<<<dim3(128), dim3(256), 0, stream>>>(w_vkq, w_out, wbf, wob);
  proj_kernel<<<dim3(2304), dim3(256), 0, stream>>>(x, wbf, b_vkq, Vr, Qr, Kr);
  attn_kernel<<<dim3(2048), dim3(384), 0, stream>>>(Vr, Qr, Kr, Obuf);
  // TIMING PROBE: out_proj launched twice (idempotent — same inputs -> identical out).
  // dur_us_this_round - 120.5 = T_outproj. Ledger: proj ~19.5, attn ~22; this decides
  // whether the remaining ~75 us is out_proj (redesign it) or fixed overhead (fuse kernels).
  out_proj_kernel<<<dim3(576), dim3(512), 0, stream>>>(Obuf, wob, b_out, out);
  out_proj_kernel<<<dim3(576), dim3(512), 0, stream>>>(Obuf, wob, b_out, out);
}

// Round 11
// 122.020 us; speedup vs baseline: 1.1680x; 1.0793x over previous
//
#include <hip/hip_runtime.h>
#include <cstdint>
#include <cstddef>

typedef float f32x4 __attribute__((ext_vector_type(4)));
typedef float f32x2 __attribute__((ext_vector_type(2)));
typedef __bf16 bf16x8 __attribute__((ext_vector_type(8)));
typedef __bf16 bf16x2 __attribute__((ext_vector_type(2)));
typedef uint32_t u32x4 __attribute__((ext_vector_type(4)));

#define TSS 9216
#define VST 9344  // O-plane row stride (bf16 elements)
#define VSF 9472  // fp8 plane stride (bytes), 16B-multiple
#define XST 72    // proj X^T LDS row stride (bf16)
#define WST 72    // out_proj W-chunk row stride (bf16)
#define RSTD 68   // out_proj A-chunk row stride in DWORDS
#define EPS 68    // proj epilogue LDS row stride (BYTES): 17 dwords, conflict-free transpose

#define FP8_SCALE 32.0f   // V,Q,K stored as fp8 of 32*value (kills denormal flush)

__device__ __forceinline__ uint32_t pack2bf(float a, float b) {
  bf16x2 v = { (__bf16)a, (__bf16)b };   // native v_cvt_pk_bf16_f32 (RNE)
  return __builtin_bit_cast(uint32_t, v);
}
__device__ __forceinline__ uint32_t pack4fp8(float a, float b, float c, float d) {
  uint32_t r = __builtin_amdgcn_cvt_pk_fp8_f32(a, b, 0, false);
  return (uint32_t)__builtin_amdgcn_cvt_pk_fp8_f32(c, d, (int)r, true);
}
// 4 packed fp8 -> 4 bf16, NO scale (x32 carried through; folded into softmax inv)
__device__ __forceinline__ uint2 fp8x4_to_bf16x4_ns(uint32_t v) {
  const f32x2 lo = __builtin_amdgcn_cvt_pk_f32_fp8((int)v, false);
  const f32x2 hi = __builtin_amdgcn_cvt_pk_f32_fp8((int)v, true);
  return uint2{pack2bf(lo[0], lo[1]), pack2bf(hi[0], hi[1])};
}

// ---------------- Kernel 0: one-time W pre-conversion ----------------
__global__ __launch_bounds__(256, 8) void wcvt_kernel(
    const float* __restrict__ w_vkq, const float* __restrict__ w_out,
    uint16_t* __restrict__ wbf, uint16_t* __restrict__ wob)
{
  const int i = blockIdx.x * 256 + threadIdx.x;
  if (i < 24576) {          // 24576 float4 = 1536*64 floats of w_vkq
    const float4 v = ((const float4*)w_vkq)[i];
    ((uint2*)wbf)[i] = uint2{pack2bf(v.x * FP8_SCALE, v.y * FP8_SCALE),
                             pack2bf(v.z * FP8_SCALE, v.w * FP8_SCALE)};
  } else {                  // 8192 float4 = 64*512 floats of w_out
    const int j = i - 24576;
    const float4 v = ((const float4*)w_out)[j];
    ((uint2*)wob)[j] = uint2{pack2bf(v.x, v.y), pack2bf(v.z, v.w)};
  }
}

// ---------------- Kernel 1: projection v2 — 1152 blocks (oh-halves) -------------------------
// THIS ROUND'S ONE CHANGE. Ledger (R8-R10 probes): proj ~19.5 us vs ~10.5 floor; the gap is
// staging amortization: 2304 blocks each paid the x-tile staging head for only 6 o-tiles.
// Now each block covers an o-HALF (768 o): 12 o-tiles/wave, staging executed half as often
// (makespan 2.25S+13.5W -> 1.125S+13.5W) and x re-read 2x not 4x. Same fragment math, same
// accumulation order -> bit-identical. XCD grouping: the 2 oh blocks sharing an x-tile are
// 8 apart in blockIdx.
__global__ __launch_bounds__(256, 4) void proj_kernel(
    const float* __restrict__ x, const uint16_t* __restrict__ wbf,
    const float* __restrict__ b_vkq,
    uint8_t* __restrict__ Vr, uint8_t* __restrict__ Qr, uint8_t* __restrict__ Kr)
{
  __shared__ __align__(16) uint16_t Bt[64 * XST];      // X^T tile [p][c] bf16 (9.2 KB)
  __shared__ __align__(16) uint8_t  Ep[4][16 * EPS];   // per-wave transpose scratch (4.3 KB)

  const int t   = threadIdx.x;
  const int blk = blockIdx.x;        // 1152; oh in bit 3, low 3 bits = bn%8 (XCD-grouped)
  const int oh  = (blk >> 3) & 1;
  const int bn  = (blk & 7) | ((blk >> 4) << 3);
  const int nt  = bn % 144;
  const int b   = bn / 144;
  const int n0  = nt * 64;

  {
    const float* __restrict__ xb = x + (size_t)b * 64 * TSS + n0;
    const int p  = t & 63;
    const int c0 = (t >> 6) * 16;
    float v[16];
    #pragma unroll
    for (int i = 0; i < 16; ++i) v[i] = xb[(size_t)(c0 + i) * TSS + p];
    #pragma unroll
    for (int h = 0; h < 2; ++h)
      *(uint4*)&Bt[p * XST + c0 + h*8] =
        uint4{pack2bf(v[h*8+0], v[h*8+1]), pack2bf(v[h*8+2], v[h*8+3]),
              pack2bf(v[h*8+4], v[h*8+5]), pack2bf(v[h*8+6], v[h*8+7])};
  }
  __syncthreads();

  const int L    = t & 63;
  const int w    = t >> 6;
  const int lcol = L & 15;
  const int lq   = L >> 4;

  bf16x8 af[4][2];   // A = X^T, m = p (4 tiles of 16) — invariant all 12 o-tiles
  #pragma unroll
  for (int tm = 0; tm < 4; ++tm)
    #pragma unroll
    for (int ks = 0; ks < 2; ++ks)
      af[tm][ks] = *(const bf16x8*)&Bt[(tm*16 + lcol) * XST + ks*32 + lq*8];

  const int obase = oh * 768 + w * 192;   // wave's 12 o-tiles (192 contiguous o)

  bf16x8 bw[3][2];
  float  bias_r[3];
  #pragma unroll
  for (int pre = 0; pre < 3; ++pre) {
    const int o = obase + pre*16 + lcol;
    #pragma unroll
    for (int ks = 0; ks < 2; ++ks)
      bw[pre][ks] = *(const bf16x8*)(wbf + (size_t)o * 64 + ks*32 + lq*8);
    bias_r[pre] = b_vkq[o] * FP8_SCALE;
  }

  uint8_t* __restrict__ ep = Ep[w];

  #pragma unroll
  for (int ot = 0; ot < 12; ++ot) {
    const int s3   = ot % 3;
    const float bias = bias_r[s3];
    f32x4 acc[4];
    #pragma unroll
    for (int tm = 0; tm < 4; ++tm) acc[tm] = f32x4{bias, bias, bias, bias};
    #pragma unroll
    for (int tm = 0; tm < 4; ++tm)
      #pragma unroll
      for (int ks = 0; ks < 2; ++ks)
        acc[tm] = __builtin_amdgcn_mfma_f32_16x16x32_bf16(af[tm][ks], bw[s3][ks], acc[tm], 0, 0, 0);
    if (ot < 9) {
      const int on = obase + (ot + 3)*16 + lcol;
      #pragma unroll
      for (int ks = 0; ks < 2; ++ks)
        bw[s3][ks] = *(const bf16x8*)(wbf + (size_t)on * 64 + ks*32 + lq*8);
      bias_r[s3] = b_vkq[on] * FP8_SCALE;
    }
    // transpose D[p][o] -> [o][p] through wave-private LDS (in-order per wave, no barrier)
    #pragma unroll
    for (int tm = 0; tm < 4; ++tm)
      *(uint32_t*)&ep[lcol * EPS + tm*16 + lq*4] =
        pack4fp8(acc[tm][0], acc[tm][1], acc[tm][2], acc[tm][3]);

    const int o_t  = obase + ot * 16;
    const int sreg = o_t >> 9;   // 0=V 1=Q 2=K (16-tile never straddles a 512 boundary)
    uint8_t* __restrict__ reg = (sreg == 0) ? Vr : ((sreg == 1) ? Qr : Kr);
    const size_t rb = (size_t)(b * 512 + (o_t & 511)) * VSF + n0;
    #pragma unroll
    for (int s = 0; s < 4; ++s) {
      const int orow = s*4 + lq;
      const uint32_t d = *(const uint32_t*)&ep[orow * EPS + lcol*4];
      *(uint32_t*)(reg + rb + (size_t)orow * VSF + lcol*4) = d;   // 4 full 64-B rows / instr
    }
  }
}

// ---------------- Kernel 2: attention (R7-exact; T_attn ~= 22 us incl gap, R8 probe) --------
__global__ __launch_bounds__(384, 4) void attn_kernel(
    const uint8_t* __restrict__ Vr, const uint8_t* __restrict__ Qr,
    const uint8_t* __restrict__ Kr, uint16_t* __restrict__ Obuf)
{
  __shared__ __align__(16) uint8_t KQ[29952];

  const int t   = threadIdx.x;
  const int blk = blockIdx.x;
  const int b   = blk >> 9;
  const int hc  = blk & 511;
  const size_t pb8 = (size_t)(b * 512 + hc) * VSF;
  const uint8_t* __restrict__ vplane = Vr + pb8;

  const uint4* __restrict__ sk = (const uint4*)(Kr + pb8);
  const uint4* __restrict__ sq = (const uint4*)(Qr + pb8);

  // stage K now; issue Q loads now but hold in regs (LDS write deferred past QK^T)
  uint4 q0, q1;
  const int r0 = t / 6, s0 = t % 6;
  int r1 = 0, s1 = 0;
  q0 = sq[t];
  *(uint4*)&KQ[9984 + r0 * 104 + s0 * 16] = sk[t];
  if (t < 192) {
    const int g = t + 384;
    r1 = g / 6; s1 = g % 6;
    q1 = sq[g];
    *(uint4*)&KQ[9984 + r1 * 104 + s1 * 16] = sk[g];
  }

  const int L    = t & 63;
  const int w    = t / 64;
  const int lcol = L & 15;
  const int lq   = L >> 4;
  const int xrow = 16 * w + lcol;
  // scores carry FP8_SCALE^2 = 1024x; fold into exp2 constant
  const float C  = 1.44269504088896f / (9216.0f * (FP8_SCALE * FP8_SCALE));
  const f32x4 zero4 = {0.f, 0.f, 0.f, 0.f};

  // V B-frags straight from global (own rows only): 8 consecutive fp8 = one b64
  long bv[3];
  #pragma unroll
  for (int ks = 0; ks < 3; ++ks)
    bv[ks] = *(const long*)(vplane + (size_t)xrow * 96 + ks*32 + lq*8);

  __syncthreads();   // barrier A: K staged (Q loads drain here too, but writes are deferred)

  // scores D[z][x]: A = K z-tiles, B = V x-rows (fp8 MFMA)
  f32x4 sa[6];
  #pragma unroll
  for (int i = 0; i < 6; ++i) sa[i] = zero4;
  #pragma unroll
  for (int tz = 0; tz < 6; ++tz)
    #pragma unroll
    for (int ks = 0; ks < 3; ++ks) {
      const long ak = *(const long*)&KQ[9984 + (tz*16 + lcol) * 104 + ks*32 + lq*8];
      sa[tz] = __builtin_amdgcn_mfma_f32_16x16x32_fp8_fp8(ak, bv[ks], sa[tz], 0, 0, 0);
    }

  // write Q (fp8) to its own LDS region — races nothing (region unused until after
  // barrier B); ds-write latency hides under the softmax VALU below
  *(uint4*)&KQ[r0 * 104 + s0 * 16] = q0;
  if (t < 192)
    *(uint4*)&KQ[r1 * 104 + s1 * 16] = q1;

  // softmax over z (|s_true| <= 0.007 -> max-subtraction safely dropped)
  float s = 0.f;
  #pragma unroll
  for (int tz = 0; tz < 6; ++tz)
    #pragma unroll
    for (int r = 0; r < 4; ++r) {
      const float e = __builtin_exp2f(sa[tz][r] * C);
      sa[tz][r] = e;
      s += e;
    }
  s += __shfl_xor(s, 16, 64);
  s += __shfl_xor(s, 32, 64);
  // inv folds BOTH the softmax normalization and the Q x32 carried scale
  const float inv = 1.0f / (s * FP8_SCALE);

  __syncthreads();   // barrier B: Q visible to all; all waves done reading K -> P may overwrite

  // P bf16 over the K region (base 9984, stride 208 B)
  #pragma unroll
  for (int tz = 0; tz < 6; ++tz) {
    const float p0 = sa[tz][0] * inv;
    const float p1 = sa[tz][1] * inv;
    const float p2 = sa[tz][2] * inv;
    const float p3 = sa[tz][3] * inv;
    *(uint2*)&KQ[9984 + xrow * 208 + tz*32 + lq*8] = uint2{pack2bf(p0, p1), pack2bf(p2, p3)};
  }

  // PV D[z'][x]: A = Q z'-tiles (fp8 LDS -> bf16 regs, x32), B = P x-rows (own-wave LDS)
  bf16x8 bp[3];
  #pragma unroll
  for (int ks = 0; ks < 3; ++ks)
    bp[ks] = *(const bf16x8*)&KQ[9984 + xrow * 208 + ks*64 + lq*16];
  f32x4 oa[6];
  #pragma unroll
  for (int i = 0; i < 6; ++i) oa[i] = zero4;
  #pragma unroll
  for (int tz = 0; tz < 6; ++tz)
    #pragma unroll
    for (int ks = 0; ks < 3; ++ks) {
      const uint2 qraw = *(const uint2*)&KQ[(tz*16 + lcol) * 104 + ks*32 + lq*8];
      const uint2 a0 = fp8x4_to_bf16x4_ns(qraw.x);
      const uint2 a1 = fp8x4_to_bf16x4_ns(qraw.y);
      const bf16x8 aq = __builtin_bit_cast(bf16x8, uint4{a0.x, a0.y, a1.x, a1.y});
      oa[tz] = __builtin_amdgcn_mfma_f32_16x16x32_bf16(aq, bp[ks], oa[tz], 0, 0, 0);
    }

  // store O[x][z'] bf16; 4 consecutive z' per lane -> dwordx2
  uint16_t* __restrict__ dst = Obuf + (size_t)(b * 512 + hc) * VST;
  #pragma unroll
  for (int tz = 0; tz < 6; ++tz)
    *(uint2*)(dst + (size_t)xrow * 96 + tz*16 + lq*4) =
      uint2{pack2bf(oa[tz][0], oa[tz][1]), pack2bf(oa[tz][2], oa[tz][3])};
}

// ---------------- Kernel 3 (MFMA GEMM): R6-exact (T_outproj ~= 11.2 us incl gap, R10) -------
__global__ __launch_bounds__(512, 4) void out_proj_kernel(
    const uint16_t* __restrict__ Obuf, const uint16_t* __restrict__ wob,
    const float* __restrict__ b_out, float* __restrict__ out)
{
  __shared__ __align__(16) uint32_t As2[2][32 * RSTD];
  __shared__ __align__(16) uint16_t Wl[2][64 * WST];

  const int t    = threadIdx.x;
  const int blk  = blockIdx.x;          // 576 = 4b * 144 nt
  const int nt   = blk % 144;
  const int b    = blk / 144;
  const int n0   = nt * 64;
  const int L    = t & 63;
  const int w    = t >> 6;              // 0..7
  const int wo   = w >> 1;              // o-tile 0..3
  const int wp   = w & 1;               // p-pair 0..1
  const int lcol = L & 15;
  const int lq   = L >> 4;
  const int kp_g = t >> 4;              // 0..31: all packed-k rows, one per thread
  const int seg  = t & 15;              // 16 segs x 2 dwords

  const uint16_t* __restrict__ ab = Obuf + (size_t)b * 512 * VST;

  uint2 pa[2];
  uint2 pwb[2];

  auto load_chunk = [&](int k0) {
    const int ke = k0 + 2*kp_g, ko = ke + 1;
    const int pe = ((ke & 7) << 6) | (ke >> 3);
    const int po = ((ko & 7) << 6) | (ko >> 3);
    pa[0] = *(const uint2*)(ab + (size_t)pe * VST + n0 + seg * 4);
    pa[1] = *(const uint2*)(ab + (size_t)po * VST + n0 + seg * 4);
    #pragma unroll
    for (int i = 0; i < 2; ++i) {
      const int idx = t + i * 512;
      pwb[i] = *(const uint2*)(wob + (size_t)(idx >> 4) * 512 + k0 + (idx & 15) * 4);
    }
  };

  auto store_chunk = [&](int buf) {
    {
      const uint2 a = pa[0], bb = pa[1];
      uint4 d;
      d.x = (a.x & 0xffffu) | (bb.x << 16);
      d.y = (a.x >> 16)     | (bb.x & 0xffff0000u);
      d.z = (a.y & 0xffffu) | (bb.y << 16);
      d.w = (a.y >> 16)     | (bb.y & 0xffff0000u);
      *(uint4*)&As2[buf][kp_g * RSTD + seg * 4] = d;
    }
    #pragma unroll
    for (int i = 0; i < 2; ++i) {
      const int idx = t + i * 512;
      *(uint2*)&Wl[buf][(idx >> 4) * WST + (idx & 15) * 4] = pwb[i];
    }
  };

  f32x4 acc[2];
  const f32x4 zero4 = {0.f, 0.f, 0.f, 0.f};
  #pragma unroll
  for (int tm = 0; tm < 2; ++tm) acc[tm] = zero4;

  load_chunk(0);

  for (int c = 0; c < 8; ++c) {
    const int buf = c & 1;
    store_chunk(buf);
    if (c < 7) load_chunk((c + 1) * 64);
    __syncthreads();
    #pragma unroll
    for (int ks = 0; ks < 2; ++ks) {
      const bf16x8 af = *(const bf16x8*)&Wl[buf][(wo*16 + lcol) * WST + ks*32 + lq*8];
      #pragma unroll
      for (int tm = 0; tm < 2; ++tm) {
        u32x4 bb;
        #pragma unroll
        for (int jj = 0; jj < 4; ++jj)
          bb[jj] = As2[buf][(ks*16 + lq*4 + jj) * RSTD + (wp*2 + tm)*16 + lcol];
        const bf16x8 bfr = __builtin_bit_cast(bf16x8, bb);
        acc[tm] = __builtin_amdgcn_mfma_f32_16x16x32_bf16(af, bfr, acc[tm], 0, 0, 0);
      }
    }
  }

  #pragma unroll
  for (int tm = 0; tm < 2; ++tm) {
    const int p = n0 + (wp*2 + tm)*16 + lcol;
    #pragma unroll
    for (int r = 0; r < 4; ++r) {
      const int o = wo*16 + lq*4 + r;
      out[(size_t)(b * 64 + o) * TSS + p] = acc[tm][r] + b_out[o];
    }
  }
}

extern "C" void kernel_launch(void* const* d_in, const int* in_sizes, int n_in,
                              void* d_out, int out_size, void* d_ws, size_t ws_size,
                              hipStream_t stream) {
  const float* x     = (const float*)d_in[0];
  const float* w_vkq = (const float*)d_in[1];
  const float* b_vkq = (const float*)d_in[2];
  const float* w_out = (const float*)d_in[3];
  const float* b_out = (const float*)d_in[4];
  float* out = (float*)d_out;

  uint16_t* Obuf = (uint16_t*)d_ws;                         // 2048*9344*2 = 38.3 MB (bf16 O)
  uint8_t*  Vr   = (uint8_t*)(Obuf + (size_t)2048 * VST);   // 3 fp8 regions, 19.4 MB each
  uint8_t*  Qr   = Vr + (size_t)2048 * VSF;
  uint8_t*  Kr   = Qr + (size_t)2048 * VSF;
  uint16_t* wbf  = (uint16_t*)(Kr + (size_t)2048 * VSF);    // 196 KB bf16 W_vkq (x32 pre-scaled)
  uint16_t* wob  = wbf + (size_t)98304;                     // 64 KB bf16 w_out (unscaled)

  wcvt_kernel<<<dim3(128), dim3(256), 0, stream>>>(w_vkq, w_out, wbf, wob);
  proj_kernel<<<dim3(1152), dim3(256), 0, stream>>>(x, wbf, b_vkq, Vr, Qr, Kr);
  attn_kernel<<<dim3(2048), dim3(384), 0, stream>>>(Vr, Qr, Kr, Obuf);
  out_proj_kernel<<<dim3(576), dim3(512), 0, stream>>>(Obuf, wob, b_out, out);
}

// Round 12
// 120.281 us; speedup vs baseline: 1.1849x; 1.0145x over previous
//
#include <hip/hip_runtime.h>
#include <cstdint>
#include <cstddef>

typedef float f32x4 __attribute__((ext_vector_type(4)));
typedef float f32x2 __attribute__((ext_vector_type(2)));
typedef __bf16 bf16x8 __attribute__((ext_vector_type(8)));
typedef __bf16 bf16x2 __attribute__((ext_vector_type(2)));
typedef uint32_t u32x4 __attribute__((ext_vector_type(4)));

#define TSS 9216
#define VST 9344  // O-plane row stride (bf16 elements)
#define VSF 9472  // fp8 plane stride (bytes), 16B-multiple
#define XST 72    // proj X^T LDS row stride (bf16)
#define WST 72    // out_proj W-chunk row stride (bf16)
#define RSTD 68   // out_proj A-chunk row stride in DWORDS
#define EPS 68    // proj epilogue LDS row stride (BYTES): 17 dwords, conflict-free transpose

#define FP8_SCALE 32.0f   // V,Q,K stored as fp8 of 32*value (kills denormal flush)

__device__ __forceinline__ uint32_t pack2bf(float a, float b) {
  bf16x2 v = { (__bf16)a, (__bf16)b };   // native v_cvt_pk_bf16_f32 (RNE)
  return __builtin_bit_cast(uint32_t, v);
}
__device__ __forceinline__ uint32_t pack4fp8(float a, float b, float c, float d) {
  uint32_t r = __builtin_amdgcn_cvt_pk_fp8_f32(a, b, 0, false);
  return (uint32_t)__builtin_amdgcn_cvt_pk_fp8_f32(c, d, (int)r, true);
}
// 4 packed fp8 -> 4 bf16, NO scale (x32 carried through; folded into softmax inv)
__device__ __forceinline__ uint2 fp8x4_to_bf16x4_ns(uint32_t v) {
  const f32x2 lo = __builtin_amdgcn_cvt_pk_f32_fp8((int)v, false);
  const f32x2 hi = __builtin_amdgcn_cvt_pk_f32_fp8((int)v, true);
  return uint2{pack2bf(lo[0], lo[1]), pack2bf(hi[0], hi[1])};
}

// ---------------- Kernel 0: one-time W pre-conversion ----------------
__global__ __launch_bounds__(256, 8) void wcvt_kernel(
    const float* __restrict__ w_vkq, const float* __restrict__ w_out,
    uint16_t* __restrict__ wbf, uint16_t* __restrict__ wob)
{
  const int i = blockIdx.x * 256 + threadIdx.x;
  if (i < 24576) {          // 24576 float4 = 1536*64 floats of w_vkq
    const float4 v = ((const float4*)w_vkq)[i];
    ((uint2*)wbf)[i] = uint2{pack2bf(v.x * FP8_SCALE, v.y * FP8_SCALE),
                             pack2bf(v.z * FP8_SCALE, v.w * FP8_SCALE)};
  } else {                  // 8192 float4 = 64*512 floats of w_out
    const int j = i - 24576;
    const float4 v = ((const float4*)w_out)[j];
    ((uint2*)wob)[j] = uint2{pack2bf(v.x, v.y), pack2bf(v.z, v.w)};
  }
}

// ---------------- Kernel 1: projection (R4-exact — measured best; 2304 blocks) --------------
// R11's 1152-block oh-halves re-tile was +1.5 us: staging heads were already latency-hidden
// by co-resident blocks at 9 blocks/CU; halving them only lengthened the per-block tail.
__global__ __launch_bounds__(256, 4) void proj_kernel(
    const float* __restrict__ x, const uint16_t* __restrict__ wbf,
    const float* __restrict__ b_vkq,
    uint8_t* __restrict__ Vr, uint8_t* __restrict__ Qr, uint8_t* __restrict__ Kr)
{
  __shared__ __align__(16) uint16_t Bt[64 * XST];      // X^T tile [p][c] bf16 (9.2 KB)
  __shared__ __align__(16) uint8_t  Ep[4][16 * EPS];   // per-wave transpose scratch (4.3 KB)

  const int t   = threadIdx.x;
  const int blk = blockIdx.x;        // 2304; XCD-grouped: oq in bits [3:4], low 3 bits = bn%8
  const int oq  = (blk >> 3) & 3;
  const int bn  = (blk & 7) | ((blk >> 5) << 3);
  const int nt  = bn % 144;
  const int b   = bn / 144;
  const int n0  = nt * 64;

  {
    const float* __restrict__ xb = x + (size_t)b * 64 * TSS + n0;
    const int p  = t & 63;
    const int c0 = (t >> 6) * 16;
    float v[16];
    #pragma unroll
    for (int i = 0; i < 16; ++i) v[i] = xb[(size_t)(c0 + i) * TSS + p];
    #pragma unroll
    for (int h = 0; h < 2; ++h)
      *(uint4*)&Bt[p * XST + c0 + h*8] =
        uint4{pack2bf(v[h*8+0], v[h*8+1]), pack2bf(v[h*8+2], v[h*8+3]),
              pack2bf(v[h*8+4], v[h*8+5]), pack2bf(v[h*8+6], v[h*8+7])};
  }
  __syncthreads();

  const int L    = t & 63;
  const int w    = t >> 6;
  const int lcol = L & 15;
  const int lq   = L >> 4;

  bf16x8 af[4][2];   // A = X^T, m = p (4 tiles of 16) — invariant all 6 o-tiles
  #pragma unroll
  for (int tm = 0; tm < 4; ++tm)
    #pragma unroll
    for (int ks = 0; ks < 2; ++ks)
      af[tm][ks] = *(const bf16x8*)&Bt[(tm*16 + lcol) * XST + ks*32 + lq*8];

  const int obase = oq * 384 + w * 96;   // wave's 6 o-tiles

  bf16x8 bw[3][2];
  float  bias_r[3];
  #pragma unroll
  for (int pre = 0; pre < 3; ++pre) {
    const int o = obase + pre*16 + lcol;
    #pragma unroll
    for (int ks = 0; ks < 2; ++ks)
      bw[pre][ks] = *(const bf16x8*)(wbf + (size_t)o * 64 + ks*32 + lq*8);
    bias_r[pre] = b_vkq[o] * FP8_SCALE;
  }

  uint8_t* __restrict__ ep = Ep[w];

  #pragma unroll
  for (int ot = 0; ot < 6; ++ot) {
    const int s3   = ot % 3;
    const float bias = bias_r[s3];
    f32x4 acc[4];
    #pragma unroll
    for (int tm = 0; tm < 4; ++tm) acc[tm] = f32x4{bias, bias, bias, bias};
    #pragma unroll
    for (int tm = 0; tm < 4; ++tm)
      #pragma unroll
      for (int ks = 0; ks < 2; ++ks)
        acc[tm] = __builtin_amdgcn_mfma_f32_16x16x32_bf16(af[tm][ks], bw[s3][ks], acc[tm], 0, 0, 0);
    if (ot < 3) {
      const int on = obase + (ot + 3)*16 + lcol;
      #pragma unroll
      for (int ks = 0; ks < 2; ++ks)
        bw[s3][ks] = *(const bf16x8*)(wbf + (size_t)on * 64 + ks*32 + lq*8);
      bias_r[s3] = b_vkq[on] * FP8_SCALE;
    }
    // transpose D[p][o] -> [o][p] through wave-private LDS (in-order per wave, no barrier)
    #pragma unroll
    for (int tm = 0; tm < 4; ++tm)
      *(uint32_t*)&ep[lcol * EPS + tm*16 + lq*4] =
        pack4fp8(acc[tm][0], acc[tm][1], acc[tm][2], acc[tm][3]);

    const int o_t  = obase + ot * 16;
    const int sreg = o_t >> 9;   // 0=V 1=Q 2=K (16-tile never straddles a 512 boundary)
    uint8_t* __restrict__ reg = (sreg == 0) ? Vr : ((sreg == 1) ? Qr : Kr);
    const size_t rb = (size_t)(b * 512 + (o_t & 511)) * VSF + n0;
    #pragma unroll
    for (int s = 0; s < 4; ++s) {
      const int orow = s*4 + lq;
      const uint32_t d = *(const uint32_t*)&ep[orow * EPS + lcol*4];
      *(uint32_t*)(reg + rb + (size_t)orow * VSF + lcol*4) = d;   // 4 full 64-B rows / instr
    }
  }
}

// ---------------- Kernel 2: attention (R7-exact; T_attn ~= 22 us incl gap, R8 probe) --------
__global__ __launch_bounds__(384, 4) void attn_kernel(
    const uint8_t* __restrict__ Vr, const uint8_t* __restrict__ Qr,
    const uint8_t* __restrict__ Kr, uint16_t* __restrict__ Obuf)
{
  __shared__ __align__(16) uint8_t KQ[29952];

  const int t   = threadIdx.x;
  const int blk = blockIdx.x;
  const int b   = blk >> 9;
  const int hc  = blk & 511;
  const size_t pb8 = (size_t)(b * 512 + hc) * VSF;
  const uint8_t* __restrict__ vplane = Vr + pb8;

  const uint4* __restrict__ sk = (const uint4*)(Kr + pb8);
  const uint4* __restrict__ sq = (const uint4*)(Qr + pb8);

  // stage K now; issue Q loads now but hold in regs (LDS write deferred past QK^T)
  uint4 q0, q1;
  const int r0 = t / 6, s0 = t % 6;
  int r1 = 0, s1 = 0;
  q0 = sq[t];
  *(uint4*)&KQ[9984 + r0 * 104 + s0 * 16] = sk[t];
  if (t < 192) {
    const int g = t + 384;
    r1 = g / 6; s1 = g % 6;
    q1 = sq[g];
    *(uint4*)&KQ[9984 + r1 * 104 + s1 * 16] = sk[g];
  }

  const int L    = t & 63;
  const int w    = t / 64;
  const int lcol = L & 15;
  const int lq   = L >> 4;
  const int xrow = 16 * w + lcol;
  // scores carry FP8_SCALE^2 = 1024x; fold into exp2 constant
  const float C  = 1.44269504088896f / (9216.0f * (FP8_SCALE * FP8_SCALE));
  const f32x4 zero4 = {0.f, 0.f, 0.f, 0.f};

  // V B-frags straight from global (own rows only): 8 consecutive fp8 = one b64
  long bv[3];
  #pragma unroll
  for (int ks = 0; ks < 3; ++ks)
    bv[ks] = *(const long*)(vplane + (size_t)xrow * 96 + ks*32 + lq*8);

  __syncthreads();   // barrier A: K staged (Q loads drain here too, but writes are deferred)

  // scores D[z][x]: A = K z-tiles, B = V x-rows (fp8 MFMA)
  f32x4 sa[6];
  #pragma unroll
  for (int i = 0; i < 6; ++i) sa[i] = zero4;
  #pragma unroll
  for (int tz = 0; tz < 6; ++tz)
    #pragma unroll
    for (int ks = 0; ks < 3; ++ks) {
      const long ak = *(const long*)&KQ[9984 + (tz*16 + lcol) * 104 + ks*32 + lq*8];
      sa[tz] = __builtin_amdgcn_mfma_f32_16x16x32_fp8_fp8(ak, bv[ks], sa[tz], 0, 0, 0);
    }

  // write Q (fp8) to its own LDS region — races nothing (region unused until after
  // barrier B); ds-write latency hides under the softmax VALU below
  *(uint4*)&KQ[r0 * 104 + s0 * 16] = q0;
  if (t < 192)
    *(uint4*)&KQ[r1 * 104 + s1 * 16] = q1;

  // softmax over z (|s_true| <= 0.007 -> max-subtraction safely dropped)
  float s = 0.f;
  #pragma unroll
  for (int tz = 0; tz < 6; ++tz)
    #pragma unroll
    for (int r = 0; r < 4; ++r) {
      const float e = __builtin_exp2f(sa[tz][r] * C);
      sa[tz][r] = e;
      s += e;
    }
  s += __shfl_xor(s, 16, 64);
  s += __shfl_xor(s, 32, 64);
  // inv folds BOTH the softmax normalization and the Q x32 carried scale
  const float inv = 1.0f / (s * FP8_SCALE);

  __syncthreads();   // barrier B: Q visible to all; all waves done reading K -> P may overwrite

  // P bf16 over the K region (base 9984, stride 208 B)
  #pragma unroll
  for (int tz = 0; tz < 6; ++tz) {
    const float p0 = sa[tz][0] * inv;
    const float p1 = sa[tz][1] * inv;
    const float p2 = sa[tz][2] * inv;
    const float p3 = sa[tz][3] * inv;
    *(uint2*)&KQ[9984 + xrow * 208 + tz*32 + lq*8] = uint2{pack2bf(p0, p1), pack2bf(p2, p3)};
  }

  // PV D[z'][x]: A = Q z'-tiles (fp8 LDS -> bf16 regs, x32), B = P x-rows (own-wave LDS)
  bf16x8 bp[3];
  #pragma unroll
  for (int ks = 0; ks < 3; ++ks)
    bp[ks] = *(const bf16x8*)&KQ[9984 + xrow * 208 + ks*64 + lq*16];
  f32x4 oa[6];
  #pragma unroll
  for (int i = 0; i < 6; ++i) oa[i] = zero4;
  #pragma unroll
  for (int tz = 0; tz < 6; ++tz)
    #pragma unroll
    for (int ks = 0; ks < 3; ++ks) {
      const uint2 qraw = *(const uint2*)&KQ[(tz*16 + lcol) * 104 + ks*32 + lq*8];
      const uint2 a0 = fp8x4_to_bf16x4_ns(qraw.x);
      const uint2 a1 = fp8x4_to_bf16x4_ns(qraw.y);
      const bf16x8 aq = __builtin_bit_cast(bf16x8, uint4{a0.x, a0.y, a1.x, a1.y});
      oa[tz] = __builtin_amdgcn_mfma_f32_16x16x32_bf16(aq, bp[ks], oa[tz], 0, 0, 0);
    }

  // store O[x][z'] bf16; 4 consecutive z' per lane -> dwordx2
  uint16_t* __restrict__ dst = Obuf + (size_t)(b * 512 + hc) * VST;
  #pragma unroll
  for (int tz = 0; tz < 6; ++tz)
    *(uint2*)(dst + (size_t)xrow * 96 + tz*16 + lq*4) =
      uint2{pack2bf(oa[tz][0], oa[tz][1]), pack2bf(oa[tz][2], oa[tz][3])};
}

// ---------------- Kernel 3 (MFMA GEMM): R6-exact (T_outproj ~= 11.2 us incl gap, R10) -------
__global__ __launch_bounds__(512, 4) void out_proj_kernel(
    const uint16_t* __restrict__ Obuf, const uint16_t* __restrict__ wob,
    const float* __restrict__ b_out, float* __restrict__ out)
{
  __shared__ __align__(16) uint32_t As2[2][32 * RSTD];
  __shared__ __align__(16) uint16_t Wl[2][64 * WST];

  const int t    = threadIdx.x;
  const int blk  = blockIdx.x;          // 576 = 4b * 144 nt
  const int nt   = blk % 144;
  const int b    = blk / 144;
  const int n0   = nt * 64;
  const int L    = t & 63;
  const int w    = t >> 6;              // 0..7
  const int wo   = w >> 1;              // o-tile 0..3
  const int wp   = w & 1;               // p-pair 0..1
  const int lcol = L & 15;
  const int lq   = L >> 4;
  const int kp_g = t >> 4;              // 0..31: all packed-k rows, one per thread
  const int seg  = t & 15;              // 16 segs x 2 dwords

  const uint16_t* __restrict__ ab = Obuf + (size_t)b * 512 * VST;

  uint2 pa[2];
  uint2 pwb[2];

  auto load_chunk = [&](int k0) {
    const int ke = k0 + 2*kp_g, ko = ke + 1;
    const int pe = ((ke & 7) << 6) | (ke >> 3);
    const int po = ((ko & 7) << 6) | (ko >> 3);
    pa[0] = *(const uint2*)(ab + (size_t)pe * VST + n0 + seg * 4);
    pa[1] = *(const uint2*)(ab + (size_t)po * VST + n0 + seg * 4);
    #pragma unroll
    for (int i = 0; i < 2; ++i) {
      const int idx = t + i * 512;
      pwb[i] = *(const uint2*)(wob + (size_t)(idx >> 4) * 512 + k0 + (idx & 15) * 4);
    }
  };

  auto store_chunk = [&](int buf) {
    {
      const uint2 a = pa[0], bb = pa[1];
      uint4 d;
      d.x = (a.x & 0xffffu) | (bb.x << 16);
      d.y = (a.x >> 16)     | (bb.x & 0xffff0000u);
      d.z = (a.y & 0xffffu) | (bb.y << 16);
      d.w = (a.y >> 16)     | (bb.y & 0xffff0000u);
      *(uint4*)&As2[buf][kp_g * RSTD + seg * 4] = d;
    }
    #pragma unroll
    for (int i = 0; i < 2; ++i) {
      const int idx = t + i * 512;
      *(uint2*)&Wl[buf][(idx >> 4) * WST + (idx & 15) * 4] = pwb[i];
    }
  };

  f32x4 acc[2];
  const f32x4 zero4 = {0.f, 0.f, 0.f, 0.f};
  #pragma unroll
  for (int tm = 0; tm < 2; ++tm) acc[tm] = zero4;

  load_chunk(0);

  for (int c = 0; c < 8; ++c) {
    const int buf = c & 1;
    store_chunk(buf);
    if (c < 7) load_chunk((c + 1) * 64);
    __syncthreads();
    #pragma unroll
    for (int ks = 0; ks < 2; ++ks) {
      const bf16x8 af = *(const bf16x8*)&Wl[buf][(wo*16 + lcol) * WST + ks*32 + lq*8];
      #pragma unroll
      for (int tm = 0; tm < 2; ++tm) {
        u32x4 bb;
        #pragma unroll
        for (int jj = 0; jj < 4; ++jj)
          bb[jj] = As2[buf][(ks*16 + lq*4 + jj) * RSTD + (wp*2 + tm)*16 + lcol];
        const bf16x8 bfr = __builtin_bit_cast(bf16x8, bb);
        acc[tm] = __builtin_amdgcn_mfma_f32_16x16x32_bf16(af, bfr, acc[tm], 0, 0, 0);
      }
    }
  }

  #pragma unroll
  for (int tm = 0; tm < 2; ++tm) {
    const int p = n0 + (wp*2 + tm)*16 + lcol;
    #pragma unroll
    for (int r = 0; r < 4; ++r) {
      const int o = wo*16 + lq*4 + r;
      out[(size_t)(b * 64 + o) * TSS + p] = acc[tm][r] + b_out[o];
    }
  }
}

extern "C" void kernel_launch(void* const* d_in, const int* in_sizes, int n_in,
                              void* d_out, int out_size, void* d_ws, size_t ws_size,
                              hipStream_t stream) {
  const float* x     = (const float*)d_in[0];
  const float* w_vkq = (const float*)d_in[1];
  const float* b_vkq = (const float*)d_in[2];
  const float* w_out = (const float*)d_in[3];
  const float* b_out = (const float*)d_in[4];
  float* out = (float*)d_out;

  uint16_t* Obuf = (uint16_t*)d_ws;                         // 2048*9344*2 = 38.3 MB (bf16 O)
  uint8_t*  Vr   = (uint8_t*)(Obuf + (size_t)2048 * VST);   // 3 fp8 regions, 19.4 MB each
  uint8_t*  Qr   = Vr + (size_t)2048 * VSF;
  uint8_t*  Kr   = Qr + (size_t)2048 * VSF;
  uint16_t* wbf  = (uint16_t*)(Kr + (size_t)2048 * VSF);    // 196 KB bf16 W_vkq (x32 pre-scaled)
  uint16_t* wob  = wbf + (size_t)98304;                     // 64 KB bf16 w_out (unscaled)

  wcvt_kernel<<<dim3(128), dim3(256), 0, stream>>>(w_vkq, w_out, wbf, wob);
  proj_kernel<<<dim3(2304), dim3(256), 0, stream>>>(x, wbf, b_vkq, Vr, Qr, Kr);
  attn_kernel<<<dim3(2048), dim3(384), 0, stream>>>(Vr, Qr, Kr, Obuf);
  out_proj_kernel<<<dim3(576), dim3(512), 0, stream>>>(Obuf, wob, b_out, out);
}